// Round 6
// baseline (410.733 us; speedup 1.0000x reference)
//
#include <hip/hip_runtime.h>

typedef __attribute__((ext_vector_type(8))) short bf16x8;
typedef __attribute__((ext_vector_type(4))) float f32x4;

__device__ __forceinline__ unsigned short f2bf(float f){
  unsigned int u = __builtin_bit_cast(unsigned int, f);
  u += 0x7fffu + ((u >> 16) & 1u);          // RTN-even
  return (unsigned short)(u >> 16);
}
__device__ __forceinline__ float bf_lo(unsigned int v){
  return __builtin_bit_cast(float, v << 16);
}
__device__ __forceinline__ float bf_hi(unsigned int v){
  return __builtin_bit_cast(float, v & 0xffff0000u);
}
__device__ __forceinline__ float lrelu(float x){ return x > 0.f ? x : 0.2f * x; }

#define GLOAD_LDS16(g, l) \
  __builtin_amdgcn_global_load_lds((const __attribute__((address_space(1))) unsigned int*)(g), \
                                   (__attribute__((address_space(3))) unsigned int*)(l), 16, 0, 0)

// ---------------- zero kernel ------------------------------------------------
__global__ __launch_bounds__(256) void k_zero(int4* __restrict__ p, int n4){
  int i = blockIdx.x * 256 + threadIdx.x;
  if (i < n4){ int4 z; z.x=0; z.y=0; z.z=0; z.w=0; p[i] = z; }
}

// ---------------- Kernel P: W (f32 [k][c]) -> bf16 W^T padded [c][136] -------
__global__ __launch_bounds__(256) void k_wprep(const float* __restrict__ W,
                                               unsigned short* __restrict__ WbfT){
  int i = blockIdx.x * 256 + threadIdx.x;   // 64 blocks * 256 = 16384
  int c = i & 127, k = i >> 7;
  WbfT[c * 136 + k] = f2bf(W[k * 128 + c]);
}

// ---------------- Kernel A: h = x@W (bf16 MFMA, persistent blocks) -----------
// 1024 blocks (4/CU, LDS-limited). W staged once per block; barrier-free
// grid-stride loop over 128-row tiles (4 waves x 2 rowtiles of 16).
__global__ __launch_bounds__(256) void k_gemm(
    const float* __restrict__ x, const unsigned short* __restrict__ WbfT,
    const float* __restrict__ attS, const float* __restrict__ attD,
    unsigned short* __restrict__ h, float* __restrict__ aS, float* __restrict__ aD,
    int N, int ntiles)
{
  __shared__ unsigned short Wt[128][136];   // 34816 B
  int tid = threadIdx.x;

  const char* wsrc = (const char*)WbfT;
  #pragma unroll
  for (int it = 0; it < 9; ++it){
    int i = it * 256 + tid;
    if (i < 2176) GLOAD_LDS16(wsrc + (size_t)i * 16, ((char*)Wt) + i * 16);
  }
  __syncthreads();   // once per block; loop below is LDS-read-only

  int wv = tid >> 6, lane = tid & 63;
  int lrow = lane & 15, lgrp = lane >> 4;

  for (int t = blockIdx.x; t < ntiles; t += gridDim.x){
    f32x4 zero; zero[0]=0.f; zero[1]=0.f; zero[2]=0.f; zero[3]=0.f;
    f32x4 acc[2][8];
    #pragma unroll
    for (int rt = 0; rt < 2; ++rt)
      #pragma unroll
      for (int ct = 0; ct < 8; ++ct) acc[rt][ct] = zero;

    int row0b = t * 128 + wv * 32;

    #pragma unroll
    for (int rt = 0; rt < 2; ++rt){
      int row0 = row0b + rt * 16;
      bf16x8 afrag[4];
      #pragma unroll
      for (int kt = 0; kt < 4; ++kt){
        int r = row0 + lrow;
        if (r >= N) r = N - 1;
        const float* xp = x + (size_t)r * 128 + kt * 32 + lgrp * 8;
        f32x4 f0 = *(const f32x4*)xp;
        f32x4 f1 = *(const f32x4*)(xp + 4);
        bf16x8 a;
        #pragma unroll
        for (int j = 0; j < 4; ++j){
          a[j]   = (short)f2bf(f0[j]);
          a[4+j] = (short)f2bf(f1[j]);
        }
        afrag[kt] = a;
      }
      #pragma unroll
      for (int kt = 0; kt < 4; ++kt){
        #pragma unroll
        for (int ct = 0; ct < 8; ++ct){
          bf16x8 b = *(const bf16x8*)&Wt[ct*16 + lrow][kt*32 + lgrp*8];
          acc[rt][ct] = __builtin_amdgcn_mfma_f32_16x16x32_bf16(b, afrag[kt], acc[rt][ct], 0, 0, 0);
        }
      }
    }

    #pragma unroll
    for (int rt = 0; rt < 2; ++rt){
      int row = row0b + rt * 16 + lrow;

      float ps[4] = {0.f,0.f,0.f,0.f}, pd[4] = {0.f,0.f,0.f,0.f};
      #pragma unroll
      for (int ct = 0; ct < 8; ++ct){
        int hh = ct >> 1;
        f32x4 s4 = *(const f32x4*)(attS + ct*16 + lgrp*4);
        f32x4 d4 = *(const f32x4*)(attD + ct*16 + lgrp*4);
        #pragma unroll
        for (int g = 0; g < 4; ++g){
          ps[hh] += acc[rt][ct][g] * s4[g];
          pd[hh] += acc[rt][ct][g] * d4[g];
        }
      }
      #pragma unroll
      for (int hh = 0; hh < 4; ++hh){
        ps[hh] += __shfl_xor(ps[hh], 16, 64);
        ps[hh] += __shfl_xor(ps[hh], 32, 64);
        pd[hh] += __shfl_xor(pd[hh], 16, 64);
        pd[hh] += __shfl_xor(pd[hh], 32, 64);
      }
      if (lgrp == 0 && row < N){
        f32x4 vs, vd;
        #pragma unroll
        for (int hh = 0; hh < 4; ++hh){ vs[hh] = ps[hh]; vd[hh] = pd[hh]; }
        *(f32x4*)(aS + (size_t)row * 4) = vs;
        *(f32x4*)(aD + (size_t)row * 4) = vd;
      }

      if (row < N){
        unsigned short* hp = h + (size_t)row * 128 + lgrp * 4;
        #pragma unroll
        for (int ct = 0; ct < 8; ++ct){
          unsigned int u0 = (unsigned int)f2bf(acc[rt][ct][0])
                          | ((unsigned int)f2bf(acc[rt][ct][1]) << 16);
          unsigned int u1 = (unsigned int)f2bf(acc[rt][ct][2])
                          | ((unsigned int)f2bf(acc[rt][ct][3]) << 16);
          uint2 u; u.x = u0; u.y = u1;
          *(uint2*)(hp + ct * 16) = u;
        }
      }
    }
  }
}

// ---------------- CSR build ----------------
__global__ __launch_bounds__(256) void k_hist(const int* __restrict__ dst, int E,
                                              int* __restrict__ deg){
  int e = blockIdx.x * 256 + threadIdx.x;
  if (e < E) atomicAdd(&deg[dst[e]], 1);
}

__global__ __launch_bounds__(256) void k_chunksum(const int* __restrict__ deg, int N,
                                                  int* __restrict__ bsum){
  __shared__ int sm[256];
  int tid = threadIdx.x;
  int base = blockIdx.x * 2048 + tid * 8;
  int s = 0;
  #pragma unroll
  for (int j = 0; j < 8; ++j) s += (base + j < N) ? deg[base + j] : 0;
  sm[tid] = s; __syncthreads();
  for (int off = 128; off > 0; off >>= 1){
    if (tid < off) sm[tid] += sm[tid + off];
    __syncthreads();
  }
  if (tid == 0) bsum[blockIdx.x] = sm[0];
}

__global__ __launch_bounds__(256) void k_scansums(int* __restrict__ bsum, int nb){
  __shared__ int sm[256];
  int tid = threadIdx.x;
  int carry = 0;
  for (int base = 0; base < nb; base += 256){
    int v = (base + tid < nb) ? bsum[base + tid] : 0;
    sm[tid] = v; __syncthreads();
    for (int off = 1; off < 256; off <<= 1){
      int t = (tid >= off) ? sm[tid - off] : 0;
      __syncthreads();
      sm[tid] += t;
      __syncthreads();
    }
    int incl = sm[tid];
    int total = sm[255];
    __syncthreads();
    if (base + tid < nb) bsum[base + tid] = carry + incl - v;
    carry += total;
  }
}

__global__ __launch_bounds__(256) void k_scanfinal(const int* __restrict__ deg,
    const int* __restrict__ bsum, int N, int E,
    int* __restrict__ rowptr, int* __restrict__ cursor){
  __shared__ int sm[256];
  int tid = threadIdx.x;
  int base = blockIdx.x * 2048 + tid * 8;
  int v[8];
  #pragma unroll
  for (int j = 0; j < 8; ++j) v[j] = (base + j < N) ? deg[base + j] : 0;
  int t = 0;
  #pragma unroll
  for (int j = 0; j < 8; ++j){ int x_ = v[j]; v[j] = t; t += x_; }
  sm[tid] = t; __syncthreads();
  for (int off = 1; off < 256; off <<= 1){
    int u = (tid >= off) ? sm[tid - off] : 0;
    __syncthreads();
    sm[tid] += u;
    __syncthreads();
  }
  int excl = sm[tid] - t;
  int off0 = bsum[blockIdx.x] + excl;
  #pragma unroll
  for (int j = 0; j < 8; ++j){
    if (base + j < N){
      int val = off0 + v[j];
      rowptr[base + j] = val;
      cursor[base + j] = val;
    }
  }
  if (blockIdx.x == 0 && tid == 0) rowptr[N] = E;
}

__global__ __launch_bounds__(256) void k_scatter(const int* __restrict__ src,
    const int* __restrict__ dst, int E, int* __restrict__ cursor,
    int* __restrict__ csr){
  int e = blockIdx.x * 256 + threadIdx.x;
  if (e < E){
    int d = dst[e];
    int p = atomicAdd(&cursor[d], 1);
    csr[p] = src[e];
  }
}

// ---------------- Kernel C: per-dst softmax-weighted aggregation + fc head ---
// 4 nodes per wave; 16 lanes per node; each lane owns 8 channels (4 dwords).
__global__ __launch_bounds__(256) void k_aggr(
    const uint4* __restrict__ h4, const float* __restrict__ aS,
    const float* __restrict__ aD, const int* __restrict__ rowptr,
    const int* __restrict__ csr, const float* __restrict__ bias,
    const float* __restrict__ fcw, const float* __restrict__ fcb,
    float* __restrict__ out, int N)
{
  int lane = threadIdx.x & 63;
  int l16  = lane & 15;
  int node = ((int)blockIdx.x * 256 + (int)threadIdx.x) >> 4;
  if (node >= N) return;
  int head = l16 >> 2;

  float ad    = aD[node * 4 + head];
  float wself = __expf(lrelu(aS[node * 4 + head] + ad));
  float wsum  = wself;

  float acc[8];
  {
    uint4 hv = h4[node * 16 + l16];
    acc[0] = wself * bf_lo(hv.x);  acc[1] = wself * bf_hi(hv.x);
    acc[2] = wself * bf_lo(hv.y);  acc[3] = wself * bf_hi(hv.y);
    acc[4] = wself * bf_lo(hv.z);  acc[5] = wself * bf_hi(hv.z);
    acc[6] = wself * bf_lo(hv.w);  acc[7] = wself * bf_hi(hv.w);
  }

  int rb = rowptr[node], re = rowptr[node + 1];
  for (int j = rb; j < re; j += 4){
    int i1 = (j + 1 < re) ? j + 1 : j;
    int i2 = (j + 2 < re) ? j + 2 : j;
    int i3 = (j + 3 < re) ? j + 3 : j;
    int s0 = csr[j], s1 = csr[i1], s2 = csr[i2], s3 = csr[i3];
    float m1 = (j + 1 < re) ? 1.f : 0.f;
    float m2 = (j + 2 < re) ? 1.f : 0.f;
    float m3 = (j + 3 < re) ? 1.f : 0.f;
    float a0 = aS[s0 * 4 + head];
    float a1 = aS[s1 * 4 + head];
    float a2 = aS[s2 * 4 + head];
    float a3 = aS[s3 * 4 + head];
    uint4 v0 = h4[s0 * 16 + l16];
    uint4 v1 = h4[s1 * 16 + l16];
    uint4 v2 = h4[s2 * 16 + l16];
    uint4 v3 = h4[s3 * 16 + l16];
    float w0 = __expf(lrelu(a0 + ad));
    float w1 = __expf(lrelu(a1 + ad)) * m1;
    float w2 = __expf(lrelu(a2 + ad)) * m2;
    float w3 = __expf(lrelu(a3 + ad)) * m3;
    wsum += w0 + w1 + w2 + w3;
    acc[0] += w0*bf_lo(v0.x) + w1*bf_lo(v1.x) + w2*bf_lo(v2.x) + w3*bf_lo(v3.x);
    acc[1] += w0*bf_hi(v0.x) + w1*bf_hi(v1.x) + w2*bf_hi(v2.x) + w3*bf_hi(v3.x);
    acc[2] += w0*bf_lo(v0.y) + w1*bf_lo(v1.y) + w2*bf_lo(v2.y) + w3*bf_lo(v3.y);
    acc[3] += w0*bf_hi(v0.y) + w1*bf_hi(v1.y) + w2*bf_hi(v2.y) + w3*bf_hi(v3.y);
    acc[4] += w0*bf_lo(v0.z) + w1*bf_lo(v1.z) + w2*bf_lo(v2.z) + w3*bf_lo(v3.z);
    acc[5] += w0*bf_hi(v0.z) + w1*bf_hi(v1.z) + w2*bf_hi(v2.z) + w3*bf_hi(v3.z);
    acc[6] += w0*bf_lo(v0.w) + w1*bf_lo(v1.w) + w2*bf_lo(v2.w) + w3*bf_lo(v3.w);
    acc[7] += w0*bf_hi(v0.w) + w1*bf_hi(v1.w) + w2*bf_hi(v2.w) + w3*bf_hi(v3.w);
  }

  float inv = 1.f / wsum;
  const float* bp = bias + l16 * 8;
  const float* fp = fcw  + l16 * 8;
  f32x4 b0 = *(const f32x4*)bp,      b1 = *(const f32x4*)(bp + 4);
  f32x4 f0 = *(const f32x4*)fp,      f1 = *(const f32x4*)(fp + 4);
  float p = 0.f;
  p += fmaxf(acc[0]*inv + b0[0], 0.f) * f0[0];
  p += fmaxf(acc[1]*inv + b0[1], 0.f) * f0[1];
  p += fmaxf(acc[2]*inv + b0[2], 0.f) * f0[2];
  p += fmaxf(acc[3]*inv + b0[3], 0.f) * f0[3];
  p += fmaxf(acc[4]*inv + b1[0], 0.f) * f1[0];
  p += fmaxf(acc[5]*inv + b1[1], 0.f) * f1[1];
  p += fmaxf(acc[6]*inv + b1[2], 0.f) * f1[2];
  p += fmaxf(acc[7]*inv + b1[3], 0.f) * f1[3];
  #pragma unroll
  for (int m = 1; m < 16; m <<= 1) p += __shfl_xor(p, m, 64);
  if (l16 == 0) out[node] = 1.f / (1.f + __expf(-(p + fcb[0])));
}

extern "C" void kernel_launch(void* const* d_in, const int* in_sizes, int n_in,
                              void* d_out, int out_size, void* d_ws, size_t ws_size,
                              hipStream_t stream) {
  const float* x    = (const float*)d_in[0];
  const int*   ei   = (const int*)  d_in[1];
  const float* W    = (const float*)d_in[2];
  const float* attS = (const float*)d_in[3];
  const float* attD = (const float*)d_in[4];
  const float* bias = (const float*)d_in[5];
  const float* fcw  = (const float*)d_in[6];
  const float* fcb  = (const float*)d_in[7];

  int N = in_sizes[0] / 128;
  int E = in_sizes[1] / 2;
  const int* srcA = ei;
  const int* dstA = ei + E;

  char* ws = (char*)d_ws;
  size_t off = 0;
  auto alloc = [&](size_t bytes) -> void* {
    void* p = ws + off;
    off += (bytes + 255) & ~(size_t)255;
    return p;
  };
  unsigned short* h  = (unsigned short*)alloc((size_t)N * 128 * 2);
  float* aS  = (float*)alloc((size_t)N * 4 * 4);
  float* aD  = (float*)alloc((size_t)N * 4 * 4);
  int* deg    = (int*)alloc((size_t)N * 4);
  int* rowptr = (int*)alloc(((size_t)N + 1) * 4);
  int* cursor = (int*)alloc((size_t)N * 4);
  int* csr    = (int*)alloc((size_t)E * 4);
  int* bsum   = (int*)alloc(4096);
  unsigned short* WbfT = (unsigned short*)alloc(128 * 136 * 2);

  int n4 = (N + 3) / 4;
  k_zero<<<(n4 + 255) / 256, 256, 0, stream>>>((int4*)deg, n4);
  k_wprep<<<64, 256, 0, stream>>>(W, WbfT);
  int ntiles = (N + 127) / 128;
  k_gemm<<<1024, 256, 0, stream>>>(x, WbfT, attS, attD, h, aS, aD, N, ntiles);
  k_hist<<<(E + 255) / 256, 256, 0, stream>>>(dstA, E, deg);
  int nb = (N + 2047) / 2048;
  k_chunksum<<<nb, 256, 0, stream>>>(deg, N, bsum);
  k_scansums<<<1, 256, 0, stream>>>(bsum, nb);
  k_scanfinal<<<nb, 256, 0, stream>>>(deg, bsum, N, E, rowptr, cursor);
  k_scatter<<<(E + 255) / 256, 256, 0, stream>>>(srcA, dstA, E, cursor, csr);
  k_aggr<<<(N + 15) / 16, 256, 0, stream>>>((const uint4*)h, aS, aD, rowptr, csr,
                                            bias, fcw, fcb, (float*)d_out, N);
}

// Round 7
// 384.219 us; speedup vs baseline: 1.0690x; 1.0690x over previous
//
#include <hip/hip_runtime.h>

typedef __attribute__((ext_vector_type(8))) short bf16x8;
typedef __attribute__((ext_vector_type(4))) float f32x4;

__device__ __forceinline__ unsigned short f2bf(float f){
  unsigned int u = __builtin_bit_cast(unsigned int, f);
  u += 0x7fffu + ((u >> 16) & 1u);          // RTN-even
  return (unsigned short)(u >> 16);
}
__device__ __forceinline__ float bf_lo(unsigned int v){
  return __builtin_bit_cast(float, v << 16);
}
__device__ __forceinline__ float bf_hi(unsigned int v){
  return __builtin_bit_cast(float, v & 0xffff0000u);
}
__device__ __forceinline__ float lrelu(float x){ return x > 0.f ? x : 0.2f * x; }

#define GLOAD_LDS16(g, l) \
  __builtin_amdgcn_global_load_lds((const __attribute__((address_space(1))) unsigned int*)(g), \
                                   (__attribute__((address_space(3))) unsigned int*)(l), 16, 0, 0)

// ---------------- Kernel I: zero deg + W (f32 [k][c]) -> bf16 W^T [c][136] ---
__global__ __launch_bounds__(256) void k_init(const float* __restrict__ W,
                                              unsigned short* __restrict__ WbfT,
                                              int4* __restrict__ deg4, int n4){
  int i = blockIdx.x * 256 + threadIdx.x;
  if (i < n4){ int4 z; z.x=0; z.y=0; z.z=0; z.w=0; deg4[i] = z; }
  if (i < 128*128){
    int c = i & 127, k = i >> 7;
    WbfT[c * 136 + k] = f2bf(W[k * 128 + c]);
  }
}

// ---------------- Kernel A: h = x@W (bf16 MFMA, async-staged streaming) ------
// 256 blocks x 256 thr (4 waves). Wave = one 16-row slice, grid-stride.
// x staged via global_load_lds into wave-private double buffers (8KB each),
// counted vmcnt(8) keeps next tile's loads in flight across compute. No
// barriers in the loop. LDS chunk-swizzle j^=(row&7) (inverse applied on the
// global source) kills the 512B-row-stride bank conflict.
__global__ __launch_bounds__(256) void k_gemm(
    const float* __restrict__ x, const unsigned short* __restrict__ WbfT,
    const float* __restrict__ attS, const float* __restrict__ attD,
    unsigned short* __restrict__ h, float* __restrict__ aS, float* __restrict__ aD,
    int N, int nslices)
{
  __shared__ unsigned short Wt[128][136];     // 34816 B
  __shared__ float xbuf[4][2][16*128];        // 4 waves x 2 bufs x 8KB = 64KB
  int tid = threadIdx.x;

  const char* wsrc = (const char*)WbfT;
  #pragma unroll
  for (int it = 0; it < 9; ++it){
    int i = it * 256 + tid;
    if (i < 2176) GLOAD_LDS16(wsrc + (size_t)i * 16, ((char*)Wt) + i * 16);
  }
  __syncthreads();   // once; loop below has no block-wide sync

  int wv = tid >> 6, lane = tid & 63;
  int lrow = lane & 15, lgrp = lane >> 4;

  int slice  = (int)blockIdx.x * 4 + wv;
  int stride = (int)gridDim.x * 4;

  // stage slice s into buf b (8 x global_load_lds, 1KB each, wave-uniform dest)
  auto STAGE = [&](int s, int b){
    char* dst0 = (char*)&xbuf[wv][b][0];
    #pragma unroll
    for (int k = 0; k < 8; ++k){
      int c = k * 64 + lane;          // LDS chunk this lane fills
      int r = c >> 5, j = c & 31;     // row, chunk-in-row
      int gr = s * 16 + r; if (gr >= N) gr = N - 1;
      const char* src = (const char*)(x + (size_t)gr * 128) + ((j ^ (r & 7)) << 4);
      GLOAD_LDS16(src, dst0 + k * 1024);
    }
  };

  if (slice < nslices) STAGE(slice, 0);
  int b = 0;

  for (int s = slice; s < nslices; s += stride){
    int nx = s + stride;
    if (nx < nslices){
      STAGE(nx, b ^ 1);
      asm volatile("s_waitcnt vmcnt(8)" ::: "memory");   // cur buf complete
    } else {
      asm volatile("s_waitcnt vmcnt(0)" ::: "memory");
    }

    // A-fragments from LDS (swizzled chunks), convert to bf16
    const f32x4* xb = (const f32x4*)&xbuf[wv][b][0];
    bf16x8 af[4];
    #pragma unroll
    for (int kt = 0; kt < 4; ++kt){
      int j0 = kt * 8 + lgrp * 2;
      f32x4 lo = xb[lrow * 32 + ( j0      ^ (lrow & 7))];
      f32x4 hi = xb[lrow * 32 + ((j0 + 1) ^ (lrow & 7))];
      bf16x8 a;
      #pragma unroll
      for (int j = 0; j < 4; ++j){
        a[j]   = (short)f2bf(lo[j]);
        a[4+j] = (short)f2bf(hi[j]);
      }
      af[kt] = a;
    }

    f32x4 acc[8];
    #pragma unroll
    for (int ct = 0; ct < 8; ++ct){ acc[ct][0]=0.f; acc[ct][1]=0.f; acc[ct][2]=0.f; acc[ct][3]=0.f; }
    #pragma unroll
    for (int kt = 0; kt < 4; ++kt){
      #pragma unroll
      for (int ct = 0; ct < 8; ++ct){
        bf16x8 bw = *(const bf16x8*)&Wt[ct*16 + lrow][kt*32 + lgrp*8];
        acc[ct] = __builtin_amdgcn_mfma_f32_16x16x32_bf16(bw, af[kt], acc[ct], 0, 0, 0);
      }
    }

    // epilogue: lane owns row = s*16+lrow, cols ct*16 + lgrp*4 + (0..3)
    int row = s * 16 + lrow;
    float ps[4] = {0.f,0.f,0.f,0.f}, pd[4] = {0.f,0.f,0.f,0.f};
    #pragma unroll
    for (int ct = 0; ct < 8; ++ct){
      int hh = ct >> 1;
      f32x4 s4 = *(const f32x4*)(attS + ct*16 + lgrp*4);
      f32x4 d4 = *(const f32x4*)(attD + ct*16 + lgrp*4);
      #pragma unroll
      for (int g = 0; g < 4; ++g){
        ps[hh] += acc[ct][g] * s4[g];
        pd[hh] += acc[ct][g] * d4[g];
      }
    }
    #pragma unroll
    for (int hh = 0; hh < 4; ++hh){
      ps[hh] += __shfl_xor(ps[hh], 16, 64);
      ps[hh] += __shfl_xor(ps[hh], 32, 64);
      pd[hh] += __shfl_xor(pd[hh], 16, 64);
      pd[hh] += __shfl_xor(pd[hh], 32, 64);
    }
    if (lgrp == 0 && row < N){
      f32x4 vs, vd;
      #pragma unroll
      for (int hh = 0; hh < 4; ++hh){ vs[hh] = ps[hh]; vd[hh] = pd[hh]; }
      *(f32x4*)(aS + (size_t)row * 4) = vs;
      *(f32x4*)(aD + (size_t)row * 4) = vd;
    }
    if (row < N){
      unsigned short* hp = h + (size_t)row * 128 + lgrp * 4;
      #pragma unroll
      for (int ct = 0; ct < 8; ++ct){
        unsigned int u0 = (unsigned int)f2bf(acc[ct][0])
                        | ((unsigned int)f2bf(acc[ct][1]) << 16);
        unsigned int u1 = (unsigned int)f2bf(acc[ct][2])
                        | ((unsigned int)f2bf(acc[ct][3]) << 16);
        uint2 u; u.x = u0; u.y = u1;
        *(uint2*)(hp + ct * 16) = u;
      }
    }
    b ^= 1;
  }
}

// ---------------- CSR build ----------------
__global__ __launch_bounds__(256) void k_hist(const int* __restrict__ dst, int E,
                                              int* __restrict__ deg){
  int e = blockIdx.x * 256 + threadIdx.x;
  if (e < E) atomicAdd(&deg[dst[e]], 1);
}

__global__ __launch_bounds__(256) void k_chunksum(const int* __restrict__ deg, int N,
                                                  int* __restrict__ bsum){
  __shared__ int sm[256];
  int tid = threadIdx.x;
  int base = blockIdx.x * 2048 + tid * 8;
  int s = 0;
  #pragma unroll
  for (int j = 0; j < 8; ++j) s += (base + j < N) ? deg[base + j] : 0;
  sm[tid] = s; __syncthreads();
  for (int off = 128; off > 0; off >>= 1){
    if (tid < off) sm[tid] += sm[tid + off];
    __syncthreads();
  }
  if (tid == 0) bsum[blockIdx.x] = sm[0];
}

__global__ __launch_bounds__(256) void k_scansums(int* __restrict__ bsum, int nb){
  __shared__ int sm[256];
  int tid = threadIdx.x;
  int carry = 0;
  for (int base = 0; base < nb; base += 256){
    int v = (base + tid < nb) ? bsum[base + tid] : 0;
    sm[tid] = v; __syncthreads();
    for (int off = 1; off < 256; off <<= 1){
      int t = (tid >= off) ? sm[tid - off] : 0;
      __syncthreads();
      sm[tid] += t;
      __syncthreads();
    }
    int incl = sm[tid];
    int total = sm[255];
    __syncthreads();
    if (base + tid < nb) bsum[base + tid] = carry + incl - v;
    carry += total;
  }
}

__global__ __launch_bounds__(256) void k_scanfinal(const int* __restrict__ deg,
    const int* __restrict__ bsum, int N, int E,
    int* __restrict__ rowptr, int* __restrict__ cursor){
  __shared__ int sm[256];
  int tid = threadIdx.x;
  int base = blockIdx.x * 2048 + tid * 8;
  int v[8];
  #pragma unroll
  for (int j = 0; j < 8; ++j) v[j] = (base + j < N) ? deg[base + j] : 0;
  int t = 0;
  #pragma unroll
  for (int j = 0; j < 8; ++j){ int x_ = v[j]; v[j] = t; t += x_; }
  sm[tid] = t; __syncthreads();
  for (int off = 1; off < 256; off <<= 1){
    int u = (tid >= off) ? sm[tid - off] : 0;
    __syncthreads();
    sm[tid] += u;
    __syncthreads();
  }
  int excl = sm[tid] - t;
  int off0 = bsum[blockIdx.x] + excl;
  #pragma unroll
  for (int j = 0; j < 8; ++j){
    if (base + j < N){
      int val = off0 + v[j];
      rowptr[base + j] = val;
      cursor[base + j] = val;
    }
  }
  if (blockIdx.x == 0 && tid == 0) rowptr[N] = E;
}

__global__ __launch_bounds__(256) void k_scatter(const int* __restrict__ src,
    const int* __restrict__ dst, int E, int* __restrict__ cursor,
    int* __restrict__ csr){
  int e = blockIdx.x * 256 + threadIdx.x;
  if (e < E){
    int d = dst[e];
    int p = atomicAdd(&cursor[d], 1);
    csr[p] = src[e];
  }
}

// ---------------- Kernel C: per-dst softmax-weighted aggregation + fc head ---
__global__ __launch_bounds__(256) void k_aggr(
    const uint4* __restrict__ h4, const float* __restrict__ aS,
    const float* __restrict__ aD, const int* __restrict__ rowptr,
    const int* __restrict__ csr, const float* __restrict__ bias,
    const float* __restrict__ fcw, const float* __restrict__ fcb,
    float* __restrict__ out, int N)
{
  int lane = threadIdx.x & 63;
  int l16  = lane & 15;
  int node = ((int)blockIdx.x * 256 + (int)threadIdx.x) >> 4;
  if (node >= N) return;
  int head = l16 >> 2;

  float ad    = aD[node * 4 + head];
  float wself = __expf(lrelu(aS[node * 4 + head] + ad));
  float wsum  = wself;

  float acc[8];
  {
    uint4 hv = h4[node * 16 + l16];
    acc[0] = wself * bf_lo(hv.x);  acc[1] = wself * bf_hi(hv.x);
    acc[2] = wself * bf_lo(hv.y);  acc[3] = wself * bf_hi(hv.y);
    acc[4] = wself * bf_lo(hv.z);  acc[5] = wself * bf_hi(hv.z);
    acc[6] = wself * bf_lo(hv.w);  acc[7] = wself * bf_hi(hv.w);
  }

  int rb = rowptr[node], re = rowptr[node + 1];
  for (int j = rb; j < re; j += 4){
    int i1 = (j + 1 < re) ? j + 1 : j;
    int i2 = (j + 2 < re) ? j + 2 : j;
    int i3 = (j + 3 < re) ? j + 3 : j;
    int s0 = csr[j], s1 = csr[i1], s2 = csr[i2], s3 = csr[i3];
    float m1 = (j + 1 < re) ? 1.f : 0.f;
    float m2 = (j + 2 < re) ? 1.f : 0.f;
    float m3 = (j + 3 < re) ? 1.f : 0.f;
    float a0 = aS[s0 * 4 + head];
    float a1 = aS[s1 * 4 + head];
    float a2 = aS[s2 * 4 + head];
    float a3 = aS[s3 * 4 + head];
    uint4 v0 = h4[s0 * 16 + l16];
    uint4 v1 = h4[s1 * 16 + l16];
    uint4 v2 = h4[s2 * 16 + l16];
    uint4 v3 = h4[s3 * 16 + l16];
    float w0 = __expf(lrelu(a0 + ad));
    float w1 = __expf(lrelu(a1 + ad)) * m1;
    float w2 = __expf(lrelu(a2 + ad)) * m2;
    float w3 = __expf(lrelu(a3 + ad)) * m3;
    wsum += w0 + w1 + w2 + w3;
    acc[0] += w0*bf_lo(v0.x) + w1*bf_lo(v1.x) + w2*bf_lo(v2.x) + w3*bf_lo(v3.x);
    acc[1] += w0*bf_hi(v0.x) + w1*bf_hi(v1.x) + w2*bf_hi(v2.x) + w3*bf_hi(v3.x);
    acc[2] += w0*bf_lo(v0.y) + w1*bf_lo(v1.y) + w2*bf_lo(v2.y) + w3*bf_lo(v3.y);
    acc[3] += w0*bf_hi(v0.y) + w1*bf_hi(v1.y) + w2*bf_hi(v2.y) + w3*bf_hi(v3.y);
    acc[4] += w0*bf_lo(v0.z) + w1*bf_lo(v1.z) + w2*bf_lo(v2.z) + w3*bf_lo(v3.z);
    acc[5] += w0*bf_hi(v0.z) + w1*bf_hi(v1.z) + w2*bf_hi(v2.z) + w3*bf_hi(v3.z);
    acc[6] += w0*bf_lo(v0.w) + w1*bf_lo(v1.w) + w2*bf_lo(v2.w) + w3*bf_lo(v3.w);
    acc[7] += w0*bf_hi(v0.w) + w1*bf_hi(v1.w) + w2*bf_hi(v2.w) + w3*bf_hi(v3.w);
  }

  float inv = 1.f / wsum;
  const float* bp = bias + l16 * 8;
  const float* fp = fcw  + l16 * 8;
  f32x4 b0 = *(const f32x4*)bp,      b1 = *(const f32x4*)(bp + 4);
  f32x4 f0 = *(const f32x4*)fp,      f1 = *(const f32x4*)(fp + 4);
  float p = 0.f;
  p += fmaxf(acc[0]*inv + b0[0], 0.f) * f0[0];
  p += fmaxf(acc[1]*inv + b0[1], 0.f) * f0[1];
  p += fmaxf(acc[2]*inv + b0[2], 0.f) * f0[2];
  p += fmaxf(acc[3]*inv + b0[3], 0.f) * f0[3];
  p += fmaxf(acc[4]*inv + b1[0], 0.f) * f1[0];
  p += fmaxf(acc[5]*inv + b1[1], 0.f) * f1[1];
  p += fmaxf(acc[6]*inv + b1[2], 0.f) * f1[2];
  p += fmaxf(acc[7]*inv + b1[3], 0.f) * f1[3];
  #pragma unroll
  for (int m = 1; m < 16; m <<= 1) p += __shfl_xor(p, m, 64);
  if (l16 == 0) out[node] = 1.f / (1.f + __expf(-(p + fcb[0])));
}

extern "C" void kernel_launch(void* const* d_in, const int* in_sizes, int n_in,
                              void* d_out, int out_size, void* d_ws, size_t ws_size,
                              hipStream_t stream) {
  const float* x    = (const float*)d_in[0];
  const int*   ei   = (const int*)  d_in[1];
  const float* W    = (const float*)d_in[2];
  const float* attS = (const float*)d_in[3];
  const float* attD = (const float*)d_in[4];
  const float* bias = (const float*)d_in[5];
  const float* fcw  = (const float*)d_in[6];
  const float* fcb  = (const float*)d_in[7];

  int N = in_sizes[0] / 128;
  int E = in_sizes[1] / 2;
  const int* srcA = ei;
  const int* dstA = ei + E;

  char* ws = (char*)d_ws;
  size_t off = 0;
  auto alloc = [&](size_t bytes) -> void* {
    void* p = ws + off;
    off += (bytes + 255) & ~(size_t)255;
    return p;
  };
  unsigned short* h  = (unsigned short*)alloc((size_t)N * 128 * 2);
  float* aS  = (float*)alloc((size_t)N * 4 * 4);
  float* aD  = (float*)alloc((size_t)N * 4 * 4);
  int* deg    = (int*)alloc((size_t)N * 4);
  int* rowptr = (int*)alloc(((size_t)N + 1) * 4);
  int* cursor = (int*)alloc((size_t)N * 4);
  int* csr    = (int*)alloc((size_t)E * 4);
  int* bsum   = (int*)alloc(4096);
  unsigned short* WbfT = (unsigned short*)alloc(128 * 136 * 2);

  int n4 = (N + 3) / 4;
  int ninit = (n4 > 16384) ? n4 : 16384;
  k_init<<<(ninit + 255) / 256, 256, 0, stream>>>(W, WbfT, (int4*)deg, n4);
  int nslices = (N + 15) / 16;
  k_gemm<<<256, 256, 0, stream>>>(x, WbfT, attS, attD, h, aS, aD, N, nslices);
  k_hist<<<(E + 255) / 256, 256, 0, stream>>>(dstA, E, deg);
  int nb = (N + 2047) / 2048;
  k_chunksum<<<nb, 256, 0, stream>>>(deg, N, bsum);
  k_scansums<<<1, 256, 0, stream>>>(bsum, nb);
  k_scanfinal<<<nb, 256, 0, stream>>>(deg, bsum, N, E, rowptr, cursor);
  k_scatter<<<(E + 255) / 256, 256, 0, stream>>>(srcA, dstA, E, cursor, csr);
  k_aggr<<<(N + 15) / 16, 256, 0, stream>>>((const uint4*)h, aS, aD, rowptr, csr,
                                            bias, fcw, fcb, (float*)d_out, N);
}